// Round 6
// baseline (13569.447 us; speedup 1.0000x reference)
//
#include <hip/hip_runtime.h>
#include <hip/hip_bf16.h>
#include <stdint.h>

typedef __attribute__((ext_vector_type(4))) float f32x4;
typedef __attribute__((ext_vector_type(8))) short bf16x8;
typedef __attribute__((ext_vector_type(8))) unsigned short us8;
typedef unsigned short u16;
typedef unsigned int u32;

#define DEV static __device__ __forceinline__

DEV u16 f2b(float f){
  u32 u = __float_as_uint(f);
  u += 0x7fffu + ((u >> 16) & 1u);
  return (u16)(u >> 16);
}
DEV float b2f(u16 h){ return __uint_as_float(((u32)h) << 16); }

// ---------------- pad & cast x : xp[b][s+3][d] = bf16(x[b][s][d]), 3 zero rows each side ----------------
__global__ void k_pad_cast(const float* __restrict__ x, u16* __restrict__ xp){
  int i8 = blockIdx.x * blockDim.x + threadIdx.x;
  int d8 = i8 % 96; int rest = i8 / 96;
  int sp = rest % 262; int b = rest / 262;
  us8 o;
  int s = sp - 3;
  if (s >= 0 && s < 256){
    const float* src = x + ((long)(b*256 + s)*768 + d8*8);
    #pragma unroll
    for (int j=0;j<8;j++) o[j] = f2b(src[j]);
  } else {
    #pragma unroll
    for (int j=0;j<8;j++) o[j] = 0;
  }
  *(us8*)(xp + (long)i8*8) = o;
}

// ---------------- V[d][c][i] f32: zero-padded per-tap conv weights ----------------
__global__ void k_build_v(const float* __restrict__ cw3, const float* __restrict__ cw5,
                          const float* __restrict__ cw7, float* __restrict__ V){
  int idx = blockIdx.x * blockDim.x + threadIdx.x;
  if (idx >= 7*768*768) return;
  int d = idx / (768*768); int rem = idx - d*(768*768);
  int c = rem / 768; int i = rem - c*768;
  int dd = d - 3;
  float v = 0.f;
  if (c < 256){ int t = dd + 1; if (t >= 0 && t < 3) v = cw3[((long)c*768 + i)*3 + t]; }
  else if (c < 512){ int t = dd + 2; if (t >= 0 && t < 5) v = cw5[((long)(c-256)*768 + i)*5 + t]; }
  else { int t = dd + 3; v = cw7[((long)(c-512)*768 + i)*7 + t]; }
  V[idx] = v;
}

// ---------------- Weff_bt[j][d*768+i] = sum_c Wx_cat[j][c] * V[d][c][i] ----------------
__global__ __launch_bounds__(256) void k_weff(
    const float* __restrict__ wxrz, const float* __restrict__ wxn,
    const float* __restrict__ V, u16* __restrict__ wt)
{
  __shared__ float As[16][64];
  __shared__ float Bs[16][64];
  const int t = threadIdx.x;
  const int it = blockIdx.x, jt = blockIdx.y, dlt = blockIdx.z;
  const float* Arow = (jt < 12) ? (wxrz + (long)jt*64*768) : (wxn + (long)(jt-12)*64*768);
  const int tx = t & 15, ty = t >> 4;
  const int jA = t >> 2, cqA = (t & 3) * 4;
  const int iB = t & 63, cB = t >> 6;
  float acc[4][4] = {};
  for (int k0 = 0; k0 < 768; k0 += 16){
    __syncthreads();
    float4 av = *(const float4*)(Arow + (long)jA*768 + k0 + cqA);
    As[cqA+0][jA] = av.x; As[cqA+1][jA] = av.y; As[cqA+2][jA] = av.z; As[cqA+3][jA] = av.w;
    #pragma unroll
    for (int l=0;l<4;l++){
      int c = cB + l*4;
      Bs[c][iB] = V[((long)dlt*768 + k0 + c)*768 + it*64 + iB];
    }
    __syncthreads();
    #pragma unroll
    for (int kk=0;kk<16;kk++){
      float4 a4 = *(const float4*)(&As[kk][ty*4]);
      float4 b4 = *(const float4*)(&Bs[kk][tx*4]);
      float aa[4] = {a4.x,a4.y,a4.z,a4.w}, bb[4] = {b4.x,b4.y,b4.z,b4.w};
      #pragma unroll
      for (int jj=0;jj<4;jj++)
        #pragma unroll
        for (int ii=0;ii<4;ii++) acc[jj][ii] += aa[jj]*bb[ii];
    }
  }
  #pragma unroll
  for (int jj=0;jj<4;jj++){
    long j = jt*64 + ty*4 + jj;
    #pragma unroll
    for (int ii=0;ii<4;ii++){
      int i = it*64 + tx*4 + ii;
      wt[j*5376 + dlt*768 + i] = f2b(acc[jj][ii]);
    }
  }
}

// ---------------- beff[j] = Wx_b[j] + sum_c Wx[j][c]*conv_b_cat[c] ----------------
__global__ void k_beff(const float* __restrict__ wxrz, const float* __restrict__ wxn,
                       const float* __restrict__ bxrz, const float* __restrict__ bxn,
                       const float* __restrict__ cb3, const float* __restrict__ cb5,
                       const float* __restrict__ cb7, float* __restrict__ beff){
  int j = blockIdx.x*blockDim.x + threadIdx.x;
  if (j >= 1152) return;
  const float* row = (j < 768) ? (wxrz + (long)j*768) : (wxn + (long)(j-768)*768);
  float s = (j < 768) ? bxrz[j] : bxn[j-768];
  for (int c=0;c<768;c++){
    float cb = (c<256) ? cb3[c] : (c<512) ? cb5[c-256] : cb7[c-512];
    s += row[c]*cb;
  }
  beff[j] = s;
}

// ---------------- pack ALL GRU weights: wpk[wave16][frag72][lane64][8] ----------------
// waves 0-7: rz. frag = f_o*12+kf; out-tile = wave*6+f_o (48 tiles over 768 outs)
// waves 8-15: n. frag = (f_o*12+kf)*2+p (p=0 hi, p=1 lo); out-tile = (wave-8)*3+f_o (24 tiles)
// B-frag element (lane,j): col n = tile*16+(lane&15), k = kf*32+(lane>>4)*8+j   [R5-verified]
__global__ void k_packw(const float* __restrict__ whrz, const float* __restrict__ whn,
                        u16* __restrict__ wpk){
  int idx = blockIdx.x*blockDim.x + threadIdx.x;
  if (idx >= 16*72*64*8) return;
  int j = idx & 7; int t = idx >> 3;
  int lane = t & 63; int t2 = t >> 6;
  int frag = t2 % 72; int wave = t2 / 72;
  u16 val;
  if (wave < 8){
    int f_o = frag / 12, kf = frag % 12;
    int jout = (wave*6 + f_o)*16 + (lane & 15);
    int k = kf*32 + (lane >> 4)*8 + j;
    val = f2b(whrz[(long)jout*384 + k]);
  } else {
    int p = frag & 1, ff = frag >> 1;
    int f_o = ff / 12, kf = ff % 12;
    int jout = ((wave-8)*3 + f_o)*16 + (lane & 15);
    int k = kf*32 + (lane >> 4)*8 + j;
    float v = whn[(long)jout*384 + k];
    u16 hi = f2b(v);
    val = p ? f2b(v - b2f(hi)) : hi;
  }
  wpk[idx] = val;
}

// ---------------- bf16 GEMM, m97 structure ----------------
template<bool F32OUT>
__global__ __launch_bounds__(256) void k_gemm(
    const u16* __restrict__ A, long a_sb, long a_ss,
    const u16* __restrict__ Bt, int K,
    const float* __restrict__ bias,
    void* __restrict__ C, int ldc, int col0)
{
  __shared__ __align__(16) u16 As[128*64];
  __shared__ __align__(16) u16 Bs[128*64];
  const int tid = threadIdx.x;
  const int wave = tid >> 6, lane = tid & 63;
  const int mt = blockIdx.x, nt = blockIdx.y;
  const long abase = (long)(mt >> 1)*a_sb + (long)((mt & 1)*128)*a_ss;
  const long bbase = (long)nt*128*K;
  const int lr = lane >> 3;
  const int lc = (lane & 7) * 8;
  const int wr = (wave >> 1)*64, wc = (wave & 1)*64;

  f32x4 acc[4][4];
  #pragma unroll
  for (int mi=0;mi<4;mi++)
    #pragma unroll
    for (int ni=0;ni<4;ni++) acc[mi][ni] = 0;

  for (int k0 = 0; k0 < K; k0 += 64){
    __syncthreads();
    #pragma unroll
    for (int a=0;a<4;a++){
      int q = wave*4 + a;
      const u16* srcA = A + abase + (long)(q*8 + lr)*a_ss + k0 + lc;
      __builtin_amdgcn_global_load_lds((const __attribute__((address_space(1))) void*)srcA,
                                       (__attribute__((address_space(3))) void*)(As + q*8*64), 16, 0, 0);
      const u16* srcB = Bt + bbase + (long)(q*8 + lr)*K + k0 + lc;
      __builtin_amdgcn_global_load_lds((const __attribute__((address_space(1))) void*)srcB,
                                       (__attribute__((address_space(3))) void*)(Bs + q*8*64), 16, 0, 0);
    }
    __syncthreads();
    #pragma unroll
    for (int kk=0;kk<2;kk++){
      const int kb = kk*32 + (lane >> 4)*8;
      bf16x8 af[4], bfr[4];
      #pragma unroll
      for (int mi=0;mi<4;mi++)
        af[mi] = *(const bf16x8*)(As + (wr + mi*16 + (lane & 15))*64 + kb);
      #pragma unroll
      for (int ni=0;ni<4;ni++)
        bfr[ni] = *(const bf16x8*)(Bs + (wc + ni*16 + (lane & 15))*64 + kb);
      #pragma unroll
      for (int mi=0;mi<4;mi++)
        #pragma unroll
        for (int ni=0;ni<4;ni++)
          acc[mi][ni] = __builtin_amdgcn_mfma_f32_16x16x32_bf16(af[mi], bfr[ni], acc[mi][ni], 0, 0, 0);
    }
  }
  const int rbase = mt*128 + wr + ((lane >> 4) << 2);
  const int cbase = nt*128 + wc + (lane & 15);
  #pragma unroll
  for (int mi=0;mi<4;mi++){
    #pragma unroll
    for (int ni=0;ni<4;ni++){
      int col = cbase + ni*16;
      float bv = bias ? bias[col] : 0.0f;
      #pragma unroll
      for (int j=0;j<4;j++){
        int row = rbase + mi*16 + j;
        if (F32OUT) ((float*)C)[(long)row*ldc + col0 + col] = acc[mi][ni][j] + bv;
        else        ((u16*)C)[(long)row*ldc + col0 + col] = f2b(acc[mi][ni][j] + bv);
      }
    }
  }
}

// ---------------- row LN on f32 scores (in-place) ----------------
__global__ __launch_bounds__(192) void k_ln1(
    float* __restrict__ sc,
    const float* __restrict__ g1, const float* __restrict__ b1,
    const float* __restrict__ g2, const float* __restrict__ b2)
{
  long row = blockIdx.x;
  float* r = sc + row*1152;
  int t = threadIdx.x;
  __shared__ float red[3][4];
  float s0=0, q0=0, s1=0, q1=0;
  float4 va, vb;
  if (t < 144){
    va = *(const float4*)(r + t*8);
    vb = *(const float4*)(r + t*8 + 4);
    float a = va.x+va.y+va.z+va.w + vb.x+vb.y+vb.z+vb.w;
    float aq = va.x*va.x+va.y*va.y+va.z*va.z+va.w*va.w
             + vb.x*vb.x+vb.y*vb.y+vb.z*vb.z+vb.w*vb.w;
    if (t < 96){ s0 = a; q0 = aq; } else { s1 = a; q1 = aq; }
  }
  int lane = t & 63, wid = t >> 6;
  #pragma unroll
  for (int o=32;o>0;o>>=1){
    s0 += __shfl_down(s0,o); q0 += __shfl_down(q0,o);
    s1 += __shfl_down(s1,o); q1 += __shfl_down(q1,o);
  }
  if (lane == 0){ red[wid][0]=s0; red[wid][1]=q0; red[wid][2]=s1; red[wid][3]=q1; }
  __syncthreads();
  float S0 = red[0][0]+red[1][0]+red[2][0];
  float Q0 = red[0][1]+red[1][1]+red[2][1];
  float S1 = red[0][2]+red[1][2]+red[2][2];
  float Q1 = red[0][3]+red[1][3]+red[2][3];
  if (t < 144){
    float mu, rs; const float *g, *bb; int cb;
    if (t < 96){ mu = S0*(1.f/768.f); rs = rsqrtf(Q0*(1.f/768.f) - mu*mu + 1e-5f); g=g1; bb=b1; cb = t*8; }
    else       { mu = S1*(1.f/384.f); rs = rsqrtf(Q1*(1.f/384.f) - mu*mu + 1e-5f); g=g2; bb=b2; cb = (t-96)*8; }
    float o[8] = {va.x,va.y,va.z,va.w,vb.x,vb.y,vb.z,vb.w};
    #pragma unroll
    for (int j=0;j<8;j++) o[j] = (o[j] - mu)*rs*g[cb+j] + bb[cb+j];
    *(float4*)(r + t*8)     = make_float4(o[0],o[1],o[2],o[3]);
    *(float4*)(r + t*8 + 4) = make_float4(o[4],o[5],o[6],o[7]);
  }
}

// ---------------- BiGRU: ONE block = 4 sequences, full weight set in VGPRs, zero cross-block comm ----------------
// 64 blocks x 1024 threads (16 waves). waves 0-7: rz matvec; waves 8-15: n matvec + gates.
// hlds rows: 0-3 = h_hi(seq0..3), 4-7 = h_lo(seq0..3), 8-15 = zero.
// MFMA C row m = (lane>>4)*4+j -> seqs live at lg==0 (rows 0-3); rows 4-7 (h_lo pass) at lg==1.
__global__ __launch_bounds__(1024, 4) void k_gru3(
    const float* __restrict__ a,        // (32768 x 1152) [r|z|n] f32, LN'd
    const u16* __restrict__ wpk,        // packed weights [16][72][64][8]
    const float* __restrict__ bhrz, const float* __restrict__ bhn,
    const float* __restrict__ g1, const float* __restrict__ b1,   // lnh1 (768)
    const float* __restrict__ g2, const float* __restrict__ b2,   // lnh2 (384)
    float* __restrict__ outr)           // (32768 x 768) [fwd|bwd] f32
{
  const int bid = blockIdx.x;
  const int dir = bid >> 5;
  const int b0  = (bid & 31) * 4;
  const int tid = threadIdx.x, lane = tid & 63, wid = tid >> 6;
  const int lc = lane & 15, lg = lane >> 4;
  const bool is_rz = wid < 8;

  __shared__ __align__(16) u16 hlds[16*392];   // rows x (384 + 8 pad)
  __shared__ float S_lds[768][4];              // rz pre-acts (biased) [jout][seq]
  __shared__ float przw[8][4][2];
  __shared__ float pnw[8][4][2];
  __shared__ float4 stats_lds[4];

  // ---- persistent weights -> 288 VGPRs/thread ----
  bf16x8 wf[72];
  {
    const u16* base = wpk + ((long)wid*72*64 + lane)*8;
    #pragma unroll
    for (int f=0; f<72; f++)
      wf[f] = *(const bf16x8*)(base + (long)f*512);
  }
  // ---- per-role constants ----
  float bias_f[6];
  int   u_f[3];
  float bhn_f[3], G1r_f[3],B1r_f[3],G1z_f[3],B1z_f[3],G2_f[3],B2_f[3];
  if (is_rz){
    #pragma unroll
    for (int f=0; f<6; f++) bias_f[f] = bhrz[(wid*6+f)*16 + lc];
  } else {
    #pragma unroll
    for (int f=0; f<3; f++){
      int u = ((wid-8)*3+f)*16 + lc;
      u_f[f] = u;
      bhn_f[f] = bhn[u];
      G1r_f[f] = g1[u];     B1r_f[f] = b1[u];
      G1z_f[f] = g1[384+u]; B1z_f[f] = b1[384+u];
      G2_f[f]  = g2[u];     B2_f[f]  = b2[u];
    }
  }
  float hprev[3][4];
  #pragma unroll
  for (int f=0;f<3;f++)
    #pragma unroll
    for (int j=0;j<4;j++) hprev[f][j] = 0.f;

  for (int i = tid; i < 16*392/2; i += 1024) ((u32*)hlds)[i] = 0;
  __syncthreads();

  #pragma unroll 1
  for (int step=0; step<256; step++){
    const int s_t = dir ? (255-step) : step;

    // ---- a loads (n-waves), issued before matvec to hide latency ----
    float av_r[3][4], av_z[3][4], av_n[3][4];
    float nf[3][4];
    if (!is_rz){
      #pragma unroll
      for (int j=0;j<4;j++){
        const float* ar = a + ((long)((b0+j)*256 + s_t))*1152;
        #pragma unroll
        for (int f=0;f<3;f++){
          av_r[f][j] = ar[u_f[f]];
          av_z[f][j] = ar[384+u_f[f]];
          av_n[f][j] = ar[768+u_f[f]];
        }
      }
    }

    // ---- matvec ----
    if (is_rz){
      f32x4 acc[6];
      #pragma unroll
      for (int f=0;f<6;f++) acc[f] = 0;
      #pragma unroll
      for (int kf=0; kf<12; kf++){
        const bf16x8 hv = *(const bf16x8*)(hlds + lc*392 + kf*32 + lg*8);
        #pragma unroll
        for (int f=0; f<6; f++)
          acc[f] = __builtin_amdgcn_mfma_f32_16x16x32_bf16(hv, wf[f*12+kf], acc[f], 0,0,0);
      }
      float sv[4] = {0,0,0,0}, qv[4] = {0,0,0,0};
      #pragma unroll
      for (int f=0; f<6; f++)
        #pragma unroll
        for (int j=0;j<4;j++){
          float v = acc[f][j] + bias_f[f];
          acc[f][j] = v;
          sv[j] += v; qv[j] += v*v;
        }
      if (lg == 0){
        #pragma unroll
        for (int f=0;f<6;f++){
          int jout = (wid*6+f)*16 + lc;
          #pragma unroll
          for (int j=0;j<4;j++) S_lds[jout][j] = acc[f][j];
        }
      }
      #pragma unroll
      for (int m=1;m<16;m<<=1)
        #pragma unroll
        for (int j=0;j<4;j++){ sv[j] += __shfl_xor(sv[j],m); qv[j] += __shfl_xor(qv[j],m); }
      if (lane==0){
        #pragma unroll
        for (int j=0;j<4;j++){ przw[wid][j][0]=sv[j]; przw[wid][j][1]=qv[j]; }
      }
    } else {
      f32x4 accA[3], accB[3];
      #pragma unroll
      for (int f=0;f<3;f++){ accA[f] = 0; accB[f] = 0; }
      #pragma unroll
      for (int kf=0; kf<12; kf++){
        const bf16x8 hv = *(const bf16x8*)(hlds + lc*392 + kf*32 + lg*8);
        #pragma unroll
        for (int f=0; f<3; f++){
          accA[f] = __builtin_amdgcn_mfma_f32_16x16x32_bf16(hv, wf[(f*12+kf)*2],   accA[f], 0,0,0);
          accB[f] = __builtin_amdgcn_mfma_f32_16x16x32_bf16(hv, wf[(f*12+kf)*2+1], accB[f], 0,0,0);
        }
      }
      // n = h_hi*W_hi (rows0-3) + h_lo*W_hi (rows4-7, via shfl) + h_hi*W_lo (rows0-3)
      float sv[4] = {0,0,0,0}, qv[4] = {0,0,0,0};
      #pragma unroll
      for (int f=0;f<3;f++)
        #pragma unroll
        for (int j=0;j<4;j++){
          float alo = __shfl_down(accA[f][j], 16);
          float v = accA[f][j] + alo + accB[f][j] + bhn_f[f];
          nf[f][j] = v;
          sv[j] += v; qv[j] += v*v;
        }
      #pragma unroll
      for (int m=1;m<16;m<<=1)
        #pragma unroll
        for (int j=0;j<4;j++){ sv[j] += __shfl_xor(sv[j],m); qv[j] += __shfl_xor(qv[j],m); }
      if (lane==0){
        #pragma unroll
        for (int j=0;j<4;j++){ pnw[wid-8][j][0]=sv[j]; pnw[wid-8][j][1]=qv[j]; }
      }
    }
    __syncthreads();   // S_lds, przw, pnw ready

    if (tid < 4){
      float s1=0,q1=0,s2=0,q2=0;
      #pragma unroll
      for (int w=0;w<8;w++){
        s1 += przw[w][tid][0]; q1 += przw[w][tid][1];
        s2 += pnw[w][tid][0];  q2 += pnw[w][tid][1];
      }
      float mu1 = s1*(1.f/768.f), rs1 = rsqrtf(q1*(1.f/768.f)-mu1*mu1+1e-5f);
      float mu2 = s2*(1.f/384.f), rs2 = rsqrtf(q2*(1.f/384.f)-mu2*mu2+1e-5f);
      stats_lds[tid] = make_float4(mu1,rs1,mu2,rs2);
    }
    __syncthreads();   // stats ready

    if (!is_rz && lg == 0){
      #pragma unroll
      for (int f=0;f<3;f++){
        int u = u_f[f];
        #pragma unroll
        for (int j=0;j<4;j++){
          float4 st = stats_lds[j];
          float rpre = S_lds[u][j], zpre = S_lds[384+u][j];
          float gr = 1.f/(1.f+__expf(-(av_r[f][j] + (rpre-st.x)*st.y*G1r_f[f] + B1r_f[f])));
          float gz = 1.f/(1.f+__expf(-(av_z[f][j] + (zpre-st.x)*st.y*G1z_f[f] + B1z_f[f])));
          float nv = tanhf(av_n[f][j] + gr*((nf[f][j]-st.z)*st.w*G2_f[f] + B2_f[f]));
          float hn = (1.f-gz)*nv + gz*hprev[f][j];
          hprev[f][j] = hn;
          outr[((long)((b0+j)*256+s_t))*768 + dir*384 + u] = hn;
          u16 hi = f2b(hn);
          hlds[j*392 + u]     = hi;
          hlds[(4+j)*392 + u] = f2b(hn - b2f(hi));
        }
      }
    }
    __syncthreads();   // h for next step ready
  }
}

// ---------------- final LN over 768 (f32 in), f32 out ----------------
__global__ __launch_bounds__(128) void k_lnout(
    const float* __restrict__ hr, const float* __restrict__ g, const float* __restrict__ bb,
    float* __restrict__ out)
{
  long row = blockIdx.x;
  const float* r = hr + row*768;
  int t = threadIdx.x;
  __shared__ float red[2][2];
  float s=0, q=0;
  float4 va, vb;
  if (t < 96){
    va = *(const float4*)(r + t*8);
    vb = *(const float4*)(r + t*8 + 4);
    s = va.x+va.y+va.z+va.w + vb.x+vb.y+vb.z+vb.w;
    q = va.x*va.x+va.y*va.y+va.z*va.z+va.w*va.w
      + vb.x*vb.x+vb.y*vb.y+vb.z*vb.z+vb.w*vb.w;
  }
  int lane = t & 63, wid = t >> 6;
  #pragma unroll
  for (int o=32;o>0;o>>=1){ s += __shfl_down(s,o); q += __shfl_down(q,o); }
  if (lane == 0){ red[wid][0]=s; red[wid][1]=q; }
  __syncthreads();
  float S = red[0][0]+red[1][0], Q = red[0][1]+red[1][1];
  float mu = S*(1.f/768.f), rs = rsqrtf(Q*(1.f/768.f) - mu*mu + 1e-5f);
  if (t < 96){
    float* op = out + row*768 + t*8;
    float iv[8] = {va.x,va.y,va.z,va.w,vb.x,vb.y,vb.z,vb.w};
    #pragma unroll
    for (int j=0;j<8;j++) op[j] = (iv[j] - mu)*rs*g[t*8+j] + bb[t*8+j];
  }
}

extern "C" void kernel_launch(void* const* d_in, const int* in_sizes, int n_in,
                              void* d_out, int out_size, void* d_ws, size_t ws_size,
                              hipStream_t stream){
  const float* x     = (const float*)d_in[0];
  const float* cw3   = (const float*)d_in[1];
  const float* cb3   = (const float*)d_in[2];
  const float* cw5   = (const float*)d_in[3];
  const float* cb5   = (const float*)d_in[4];
  const float* cw7   = (const float*)d_in[5];
  const float* cb7   = (const float*)d_in[6];
  const float* wxrz  = (const float*)d_in[7];
  const float* bxrz  = (const float*)d_in[8];
  const float* whrz  = (const float*)d_in[9];
  const float* bhrz  = (const float*)d_in[10];
  const float* wxn   = (const float*)d_in[11];
  const float* bxn   = (const float*)d_in[12];
  const float* whn   = (const float*)d_in[13];
  const float* bhn   = (const float*)d_in[14];
  const float* lnx1g = (const float*)d_in[15];
  const float* lnx1b = (const float*)d_in[16];
  const float* lnh1g = (const float*)d_in[17];
  const float* lnh1b = (const float*)d_in[18];
  const float* lnx2g = (const float*)d_in[19];
  const float* lnx2b = (const float*)d_in[20];
  const float* lnh2g = (const float*)d_in[21];
  const float* lnh2b = (const float*)d_in[22];
  const float* lnog  = (const float*)d_in[23];
  const float* lnob  = (const float*)d_in[24];

  char* w = (char*)d_ws;
  auto alloc = [&](size_t bytes)->char*{ char* p = w; w += (bytes + 255) & ~(size_t)255; return p; };
  // persistent (live through k_gru3):
  float* sc   = (float*)alloc(32768L*1152*4);     // 151 MB scores -> a
  u16*  wpk   = (u16*) alloc(16L*72*64*8*2);      // 1.15 MB packed GRU weights
  // transient (dead after main GEMM) — outr aliases:
  char* regionA = w;
  u16*  xp   = (u16*) alloc(128L*262*768*2);      // 51.5 MB
  u16*  weff = (u16*) alloc(1152L*5376*2);        // 12.4 MB
  float* V   = (float*)alloc(7L*768*768*4);       // 16.5 MB
  float* beff= (float*)alloc(1152*4);
  float* outr = (float*)regionA;                  // 100.7 MB

  k_pad_cast<<<12576, 256, 0, stream>>>(x, xp);
  k_build_v<<<16128, 256, 0, stream>>>(cw3, cw5, cw7, V);
  k_weff<<<dim3(12,18,7), 256, 0, stream>>>(wxrz, wxn, V, weff);
  k_beff<<<5, 256, 0, stream>>>(wxrz, wxn, bxrz, bxn, cb3, cb5, cb7, beff);
  k_packw<<<2304, 256, 0, stream>>>(whrz, whn, wpk);

  // a = LN(x_pad (*) Weff + beff): M=32768 N=1152 K=5376
  k_gemm<true><<<dim3(256,9), 256, 0, stream>>>(xp, 262L*768, 768, weff, 5376, beff, sc, 1152, 0);
  k_ln1<<<32768, 192, 0, stream>>>(sc, lnx1g, lnx1b, lnx2g, lnx2b);
  k_gru3<<<64, 1024, 0, stream>>>(sc, wpk, bhrz, bhn, lnh1g, lnh1b, lnh2g, lnh2b, outr);
  k_lnout<<<32768, 128, 0, stream>>>(outr, lnog, lnob, (float*)d_out);
}

// Round 7
// 3806.643 us; speedup vs baseline: 3.5647x; 3.5647x over previous
//
#include <hip/hip_runtime.h>
#include <hip/hip_bf16.h>
#include <stdint.h>

typedef __attribute__((ext_vector_type(4))) float f32x4;
typedef __attribute__((ext_vector_type(8))) short bf16x8;
typedef __attribute__((ext_vector_type(8))) unsigned short us8;
typedef unsigned short u16;
typedef unsigned int u32;
typedef unsigned long long u64;

#define DEV static __device__ __forceinline__

DEV u16 f2b(float f){
  u32 u = __float_as_uint(f);
  u += 0x7fffu + ((u >> 16) & 1u);
  return (u16)(u >> 16);
}
DEV float b2f(u16 h){ return __uint_as_float(((u32)h) << 16); }

// ---------------- zero helper (re-runs every launch: replay-safe) ----------------
__global__ void k_zero(u32* __restrict__ p, int n){
  int i = blockIdx.x*blockDim.x + threadIdx.x;
  if (i < n) p[i] = 0;
}

// ---------------- pad & cast x ----------------
__global__ void k_pad_cast(const float* __restrict__ x, u16* __restrict__ xp){
  int i8 = blockIdx.x * blockDim.x + threadIdx.x;
  int d8 = i8 % 96; int rest = i8 / 96;
  int sp = rest % 262; int b = rest / 262;
  us8 o;
  int s = sp - 3;
  if (s >= 0 && s < 256){
    const float* src = x + ((long)(b*256 + s)*768 + d8*8);
    #pragma unroll
    for (int j=0;j<8;j++) o[j] = f2b(src[j]);
  } else {
    #pragma unroll
    for (int j=0;j<8;j++) o[j] = 0;
  }
  *(us8*)(xp + (long)i8*8) = o;
}

// ---------------- V[d][c][i] ----------------
__global__ void k_build_v(const float* __restrict__ cw3, const float* __restrict__ cw5,
                          const float* __restrict__ cw7, float* __restrict__ V){
  int idx = blockIdx.x * blockDim.x + threadIdx.x;
  if (idx >= 7*768*768) return;
  int d = idx / (768*768); int rem = idx - d*(768*768);
  int c = rem / 768; int i = rem - c*768;
  int dd = d - 3;
  float v = 0.f;
  if (c < 256){ int t = dd + 1; if (t >= 0 && t < 3) v = cw3[((long)c*768 + i)*3 + t]; }
  else if (c < 512){ int t = dd + 2; if (t >= 0 && t < 5) v = cw5[((long)(c-256)*768 + i)*5 + t]; }
  else { int t = dd + 3; v = cw7[((long)(c-512)*768 + i)*7 + t]; }
  V[idx] = v;
}

// ---------------- Weff ----------------
__global__ __launch_bounds__(256) void k_weff(
    const float* __restrict__ wxrz, const float* __restrict__ wxn,
    const float* __restrict__ V, u16* __restrict__ wt)
{
  __shared__ float As[16][64];
  __shared__ float Bs[16][64];
  const int t = threadIdx.x;
  const int it = blockIdx.x, jt = blockIdx.y, dlt = blockIdx.z;
  const float* Arow = (jt < 12) ? (wxrz + (long)jt*64*768) : (wxn + (long)(jt-12)*64*768);
  const int tx = t & 15, ty = t >> 4;
  const int jA = t >> 2, cqA = (t & 3) * 4;
  const int iB = t & 63, cB = t >> 6;
  float acc[4][4] = {};
  for (int k0 = 0; k0 < 768; k0 += 16){
    __syncthreads();
    float4 av = *(const float4*)(Arow + (long)jA*768 + k0 + cqA);
    As[cqA+0][jA] = av.x; As[cqA+1][jA] = av.y; As[cqA+2][jA] = av.z; As[cqA+3][jA] = av.w;
    #pragma unroll
    for (int l=0;l<4;l++){
      int c = cB + l*4;
      Bs[c][iB] = V[((long)dlt*768 + k0 + c)*768 + it*64 + iB];
    }
    __syncthreads();
    #pragma unroll
    for (int kk=0;kk<16;kk++){
      float4 a4 = *(const float4*)(&As[kk][ty*4]);
      float4 b4 = *(const float4*)(&Bs[kk][tx*4]);
      float aa[4] = {a4.x,a4.y,a4.z,a4.w}, bb[4] = {b4.x,b4.y,b4.z,b4.w};
      #pragma unroll
      for (int jj=0;jj<4;jj++)
        #pragma unroll
        for (int ii=0;ii<4;ii++) acc[jj][ii] += aa[jj]*bb[ii];
    }
  }
  #pragma unroll
  for (int jj=0;jj<4;jj++){
    long j = jt*64 + ty*4 + jj;
    #pragma unroll
    for (int ii=0;ii<4;ii++){
      int i = it*64 + tx*4 + ii;
      wt[j*5376 + dlt*768 + i] = f2b(acc[jj][ii]);
    }
  }
}

// ---------------- beff ----------------
__global__ void k_beff(const float* __restrict__ wxrz, const float* __restrict__ wxn,
                       const float* __restrict__ bxrz, const float* __restrict__ bxn,
                       const float* __restrict__ cb3, const float* __restrict__ cb5,
                       const float* __restrict__ cb7, float* __restrict__ beff){
  int j = blockIdx.x*blockDim.x + threadIdx.x;
  if (j >= 1152) return;
  const float* row = (j < 768) ? (wxrz + (long)j*768) : (wxn + (long)(j-768)*768);
  float s = (j < 768) ? bxrz[j] : bxn[j-768];
  for (int c=0;c<768;c++){
    float cb = (c<256) ? cb3[c] : (c<512) ? cb5[c-256] : cb7[c-512];
    s += row[c]*cb;
  }
  beff[j] = s;
}

// ---------------- frag-pack Whrz: [slice8][nt3][kind r/z][kt12][lane64][8] ----------------
__global__ void k_pack_wrzf(const float* __restrict__ whrz, u16* __restrict__ wf){
  int idx = blockIdx.x*blockDim.x + threadIdx.x;
  if (idx >= 8*3*2*12*512) return;
  int j = idx & 7; int t1 = idx >> 3;
  int l = t1 & 63;  int t2 = t1 >> 6;
  int kt = t2 % 12; int t3 = t2 / 12;
  int kind = t3 & 1; int t4 = t3 >> 1;
  int nt = t4 % 3;  int sl = t4 / 3;
  int u = sl*48 + nt*16 + (l & 15);
  int k = kt*32 + (l >> 4)*8 + j;
  wf[idx] = f2b(whrz[(long)(kind*384 + u)*384 + k]);
}

// ---------------- frag-pack Whn hi/lo: [slice8][nt3][hi/lo][kt12][lane64][8] ----------------
__global__ void k_pack_wnf(const float* __restrict__ whn, u16* __restrict__ wf){
  int idx = blockIdx.x*blockDim.x + threadIdx.x;
  if (idx >= 8*3*2*12*512) return;
  int j = idx & 7; int t1 = idx >> 3;
  int l = t1 & 63;  int t2 = t1 >> 6;
  int kt = t2 % 12; int t3 = t2 / 12;
  int kind = t3 & 1; int t4 = t3 >> 1;
  int nt = t4 % 3;  int sl = t4 / 3;
  int u = sl*48 + nt*16 + (l & 15);
  int k = kt*32 + (l >> 4)*8 + j;
  float v = whn[(long)u*384 + k];
  u16 hi = f2b(v);
  wf[idx] = (kind == 0) ? hi : f2b(v - b2f(hi));
}

// ---------------- bf16 GEMM, m97 structure ----------------
template<bool F32OUT>
__global__ __launch_bounds__(256) void k_gemm(
    const u16* __restrict__ A, long a_sb, long a_ss,
    const u16* __restrict__ Bt, int K,
    const float* __restrict__ bias,
    void* __restrict__ C, int ldc, int col0)
{
  __shared__ __align__(16) u16 As[128*64];
  __shared__ __align__(16) u16 Bs[128*64];
  const int tid = threadIdx.x;
  const int wave = tid >> 6, lane = tid & 63;
  const int mt = blockIdx.x, nt = blockIdx.y;
  const long abase = (long)(mt >> 1)*a_sb + (long)((mt & 1)*128)*a_ss;
  const long bbase = (long)nt*128*K;
  const int lr = lane >> 3;
  const int lc = (lane & 7) * 8;
  const int wr = (wave >> 1)*64, wc = (wave & 1)*64;

  f32x4 acc[4][4];
  #pragma unroll
  for (int mi=0;mi<4;mi++)
    #pragma unroll
    for (int ni=0;ni<4;ni++) acc[mi][ni] = 0;

  for (int k0 = 0; k0 < K; k0 += 64){
    __syncthreads();
    #pragma unroll
    for (int a=0;a<4;a++){
      int q = wave*4 + a;
      const u16* srcA = A + abase + (long)(q*8 + lr)*a_ss + k0 + lc;
      __builtin_amdgcn_global_load_lds((const __attribute__((address_space(1))) void*)srcA,
                                       (__attribute__((address_space(3))) void*)(As + q*8*64), 16, 0, 0);
      const u16* srcB = Bt + bbase + (long)(q*8 + lr)*K + k0 + lc;
      __builtin_amdgcn_global_load_lds((const __attribute__((address_space(1))) void*)srcB,
                                       (__attribute__((address_space(3))) void*)(Bs + q*8*64), 16, 0, 0);
    }
    __syncthreads();
    #pragma unroll
    for (int kk=0;kk<2;kk++){
      const int kb = kk*32 + (lane >> 4)*8;
      bf16x8 af[4], bfr[4];
      #pragma unroll
      for (int mi=0;mi<4;mi++)
        af[mi] = *(const bf16x8*)(As + (wr + mi*16 + (lane & 15))*64 + kb);
      #pragma unroll
      for (int ni=0;ni<4;ni++)
        bfr[ni] = *(const bf16x8*)(Bs + (wc + ni*16 + (lane & 15))*64 + kb);
      #pragma unroll
      for (int mi=0;mi<4;mi++)
        #pragma unroll
        for (int ni=0;ni<4;ni++)
          acc[mi][ni] = __builtin_amdgcn_mfma_f32_16x16x32_bf16(af[mi], bfr[ni], acc[mi][ni], 0, 0, 0);
    }
  }
  const int rbase = mt*128 + wr + ((lane >> 4) << 2);
  const int cbase = nt*128 + wc + (lane & 15);
  #pragma unroll
  for (int mi=0;mi<4;mi++){
    #pragma unroll
    for (int ni=0;ni<4;ni++){
      int col = cbase + ni*16;
      float bv = bias ? bias[col] : 0.0f;
      #pragma unroll
      for (int j=0;j<4;j++){
        int row = rbase + mi*16 + j;
        if (F32OUT) ((float*)C)[(long)row*ldc + col0 + col] = acc[mi][ni][j] + bv;
        else        ((u16*)C)[(long)row*ldc + col0 + col] = f2b(acc[mi][ni][j] + bv);
      }
    }
  }
}

// ---------------- row LN on f32 scores (in-place) ----------------
__global__ __launch_bounds__(192) void k_ln1(
    float* __restrict__ sc,
    const float* __restrict__ g1, const float* __restrict__ b1,
    const float* __restrict__ g2, const float* __restrict__ b2)
{
  long row = blockIdx.x;
  float* r = sc + row*1152;
  int t = threadIdx.x;
  __shared__ float red[3][4];
  float s0=0, q0=0, s1=0, q1=0;
  float4 va, vb;
  if (t < 144){
    va = *(const float4*)(r + t*8);
    vb = *(const float4*)(r + t*8 + 4);
    float a = va.x+va.y+va.z+va.w + vb.x+vb.y+vb.z+vb.w;
    float aq = va.x*va.x+va.y*va.y+va.z*va.z+va.w*va.w
             + vb.x*vb.x+vb.y*vb.y+vb.z*vb.z+vb.w*vb.w;
    if (t < 96){ s0 = a; q0 = aq; } else { s1 = a; q1 = aq; }
  }
  int lane = t & 63, wid = t >> 6;
  #pragma unroll
  for (int o=32;o>0;o>>=1){
    s0 += __shfl_down(s0,o); q0 += __shfl_down(q0,o);
    s1 += __shfl_down(s1,o); q1 += __shfl_down(q1,o);
  }
  if (lane == 0){ red[wid][0]=s0; red[wid][1]=q0; red[wid][2]=s1; red[wid][3]=q1; }
  __syncthreads();
  float S0 = red[0][0]+red[1][0]+red[2][0];
  float Q0 = red[0][1]+red[1][1]+red[2][1];
  float S1 = red[0][2]+red[1][2]+red[2][2];
  float Q1 = red[0][3]+red[1][3]+red[2][3];
  if (t < 144){
    float mu, rs; const float *g, *bb; int cb;
    if (t < 96){ mu = S0*(1.f/768.f); rs = rsqrtf(Q0*(1.f/768.f) - mu*mu + 1e-5f); g=g1; bb=b1; cb = t*8; }
    else       { mu = S1*(1.f/384.f); rs = rsqrtf(Q1*(1.f/384.f) - mu*mu + 1e-5f); g=g2; bb=b2; cb = (t-96)*8; }
    float o[8] = {va.x,va.y,va.z,va.w,vb.x,vb.y,vb.z,vb.w};
    #pragma unroll
    for (int j=0;j<8;j++) o[j] = (o[j] - mu)*rs*g[cb+j] + bb[cb+j];
    *(float4*)(r + t*8)     = make_float4(o[0],o[1],o[2],o[3]);
    *(float4*)(r + t*8 + 4) = make_float4(o[4],o[5],o[6],o[7]);
  }
}

// ---------------- relaxed group sync: no fences, WT-atomic data, monotonic counter ----------------
DEV void gsync(u32* ctrg, u32 target){
  asm volatile("s_waitcnt vmcnt(0)" ::: "memory");   // per-wave: WT data stores committed
  __syncthreads();                                    // all waves drained (compiler adds pre-barrier waits)
  if (threadIdx.x == 0){
    __hip_atomic_fetch_add(ctrg, 1u, __ATOMIC_RELAXED, __HIP_MEMORY_SCOPE_AGENT);
    u32 v;
    do { v = __hip_atomic_load(ctrg, __ATOMIC_RELAXED, __HIP_MEMORY_SCOPE_AGENT); } while (v < target);
  }
  __syncthreads();
}

// ---------------- BiGRU: 8 groups x 8 blocks; weights in VGPRs (R5-proven); relaxed-atomic exchange ----------------
__global__ __launch_bounds__(512, 2) void k_gru2(
    const float* __restrict__ a,        // (32768 x 1152) [r|z|n] f32, LN'd
    const u16* __restrict__ wrzf,       // frag-packed Whrz
    const u16* __restrict__ wnf,        // frag-packed Whn hi/lo
    const float* __restrict__ bhrz, const float* __restrict__ bhn,
    const float* __restrict__ g1, const float* __restrict__ b1,
    const float* __restrict__ g2, const float* __restrict__ b2,
    float* __restrict__ outr,           // (32768 x 768) [fwd|bwd] f32
    u32* __restrict__ hglob,            // [8][32][384] u32 = hi | lo<<16
    u64* __restrict__ P,                // [8][8][32][2] u64 = (s,q) pairs
    u32* __restrict__ ctr)              // [8]
{
  const int bid = blockIdx.x;
  const int g = bid & 7, slice = bid >> 3;
  const int dir = g >> 2, bbase = (g & 3) * 32;
  const int tid = threadIdx.x, lane = tid & 63, wid = tid >> 6;
  const int nt = wid >> 1;
  const int kind = wid & 1;
  const bool is_mv = wid < 6;
  const bool is_n  = is_mv && kind == 1;
  const bool is_rz = is_mv && kind == 0;
  const int lc = lane & 15, lg = lane >> 4;
  const int u = slice*48 + (is_mv ? nt : 0)*16 + lc;

  __shared__ __align__(16) u16 hlds[25088];   // hi plane [32][392], lo plane at +12544
  __shared__ float S_lds[3][2][2][16][16];
  __shared__ float prz[3][2][16][2];
  __shared__ float pn_[3][2][16][2];
  __shared__ float4 stats_lds[32];

  // weights -> registers (persistent), indexed by SLICE
  bf16x8 wA[12], wB[12];
  if (is_mv){
    const u16* buf = (kind == 0) ? wrzf : wnf;
    const long b0  = ((((long)slice*3 + nt)*2 + 0)*12)*512;
    const long b1o = ((((long)slice*3 + nt)*2 + 1)*12)*512;
    #pragma unroll
    for (int kt=0; kt<12; kt++){
      wA[kt] = *(const bf16x8*)(buf + b0  + kt*512 + lane*8);
      wB[kt] = *(const bf16x8*)(buf + b1o + kt*512 + lane*8);
    }
  }
  float bias0=0, bias1=0, G1r=0,B1r=0,G1z=0,B1z=0,G2v=0,B2v=0;
  if (is_rz){ bias0 = bhrz[u]; bias1 = bhrz[384+u]; }
  if (is_n){
    bias0 = bhn[u];
    G1r = g1[u]; B1r = b1[u]; G1z = g1[384+u]; B1z = b1[384+u];
    G2v = g2[u]; B2v = b2[u];
  }
  float hprev[8];
  #pragma unroll
  for (int p=0;p<8;p++) hprev[p] = 0.f;

  u32* hg = hglob + (long)g*12288;            // [32][384] u32
  u64* Pg = P + (long)g*8*32*2;
  u32* ctrg = ctr + g;
  const int sb = tid >> 4;                    // scatter batch 0..31
  const int sl16 = tid & 15;

  for (int step=0; step<256; step++){
    const int s_t = dir ? (255-step) : step;

    // ---- phase 1: pull h from IC, scatter to LDS hi/lo planes ----
    #pragma unroll
    for (int i=0;i<12;i++){
      int up = sl16 + i*16;                   // unit-pair 0..191
      u64 v = __hip_atomic_load((u64*)(hg + sb*384 + up*2), __ATOMIC_RELAXED, __HIP_MEMORY_SCOPE_AGENT);
      u32 w0 = (u32)v, w1 = (u32)(v >> 32);
      *(u32*)(hlds + sb*392 + up*2)         = (w0 & 0xffffu) | (w1 << 16);
      *(u32*)(hlds + 12544 + sb*392 + up*2) = (w0 >> 16) | (w1 & 0xffff0000u);
    }
    __syncthreads();

    // ---- a prefetch (n waves) ----
    float a_r[8], a_z[8], a_n[8];
    if (is_n){
      #pragma unroll
      for (int mt=0;mt<2;mt++)
        #pragma unroll
        for (int j=0;j<4;j++){
          int p = mt*4+j;
          int bg = mt*16 + lg*4 + j;
          long row = ((long)((bbase+bg)*256 + s_t))*1152;
          a_r[p] = a[row + u]; a_z[p] = a[row + 384 + u]; a_n[p] = a[row + 768 + u];
        }
    }

    // ---- phase 2: matvec (MFMA) ----
    f32x4 accn[2];
    if (is_rz){
      f32x4 ar[2], az[2];
      #pragma unroll
      for (int mt=0;mt<2;mt++){ ar[mt] = {bias0,bias0,bias0,bias0}; az[mt] = {bias1,bias1,bias1,bias1}; }
      #pragma unroll
      for (int kt=0;kt<12;kt++){
        #pragma unroll
        for (int mt=0;mt<2;mt++){
          const bf16x8 av = *(const bf16x8*)(hlds + (mt*16+lc)*392 + kt*32 + lg*8);
          ar[mt] = __builtin_amdgcn_mfma_f32_16x16x32_bf16(av, wA[kt], ar[mt], 0,0,0);
          az[mt] = __builtin_amdgcn_mfma_f32_16x16x32_bf16(av, wB[kt], az[mt], 0,0,0);
        }
      }
      #pragma unroll
      for (int mt=0;mt<2;mt++){
        f32x4 sv, qv;
        #pragma unroll
        for (int j=0;j<4;j++){
          S_lds[nt][0][mt][lg*4+j][lc] = ar[mt][j];
          S_lds[nt][1][mt][lg*4+j][lc] = az[mt][j];
          sv[j] = ar[mt][j] + az[mt][j];
          qv[j] = ar[mt][j]*ar[mt][j] + az[mt][j]*az[mt][j];
        }
        #pragma unroll
        for (int m=1;m<16;m<<=1){
          #pragma unroll
          for (int j=0;j<4;j++){ sv[j] += __shfl_xor(sv[j], m); qv[j] += __shfl_xor(qv[j], m); }
        }
        if (lc == 0){
          #pragma unroll
          for (int j=0;j<4;j++){ prz[nt][mt][lg*4+j][0] = sv[j]; prz[nt][mt][lg*4+j][1] = qv[j]; }
        }
      }
    } else if (is_n){
      #pragma unroll
      for (int mt=0;mt<2;mt++) accn[mt] = {bias0,bias0,bias0,bias0};
      #pragma unroll
      for (int kt=0;kt<12;kt++){
        #pragma unroll
        for (int mt=0;mt<2;mt++){
          const bf16x8 ah = *(const bf16x8*)(hlds +         (mt*16+lc)*392 + kt*32 + lg*8);
          const bf16x8 al = *(const bf16x8*)(hlds + 12544 + (mt*16+lc)*392 + kt*32 + lg*8);
          accn[mt] = __builtin_amdgcn_mfma_f32_16x16x32_bf16(ah, wA[kt], accn[mt], 0,0,0);
          accn[mt] = __builtin_amdgcn_mfma_f32_16x16x32_bf16(al, wA[kt], accn[mt], 0,0,0);
          accn[mt] = __builtin_amdgcn_mfma_f32_16x16x32_bf16(ah, wB[kt], accn[mt], 0,0,0);
        }
      }
      #pragma unroll
      for (int mt=0;mt<2;mt++){
        f32x4 sv, qv;
        #pragma unroll
        for (int j=0;j<4;j++){ sv[j] = accn[mt][j]; qv[j] = accn[mt][j]*accn[mt][j]; }
        #pragma unroll
        for (int m=1;m<16;m<<=1){
          #pragma unroll
          for (int j=0;j<4;j++){ sv[j] += __shfl_xor(sv[j], m); qv[j] += __shfl_xor(qv[j], m); }
        }
        if (lc == 0){
          #pragma unroll
          for (int j=0;j<4;j++){ pn_[nt][mt][lg*4+j][0] = sv[j]; pn_[nt][mt][lg*4+j][1] = qv[j]; }
        }
      }
    }
    __syncthreads();

    // ---- phase 3: publish stat partials (u64 pairs, WT-atomic) ----
    if (tid < 64){
      int batch = tid >> 1, pr = tid & 1, mt = batch >> 4, row = batch & 15;
      float s, q;
      if (pr == 0){
        s = prz[0][mt][row][0] + prz[1][mt][row][0] + prz[2][mt][row][0];
        q = prz[0][mt][row][1] + prz[1][mt][row][1] + prz[2][mt][row][1];
      } else {
        s = pn_[0][mt][row][0] + pn_[1][mt][row][0] + pn_[2][mt][row][0];
        q = pn_[0][mt][row][1] + pn_[1][mt][row][1] + pn_[2][mt][row][1];
      }
      u64 pk = (u64)__float_as_uint(s) | ((u64)__float_as_uint(q) << 32);
      __hip_atomic_store(&Pg[(slice*32 + batch)*2 + pr], pk, __ATOMIC_RELAXED, __HIP_MEMORY_SCOPE_AGENT);
    }
    gsync(ctrg, (u32)(8*(2*step+1)));

    // ---- phase 4: final stats ----
    if (tid < 32){
      float s1=0,q1=0,s2=0,q2=0;
      #pragma unroll
      for (int k=0;k<8;k++){
        u64 p0 = __hip_atomic_load(&Pg[(k*32 + tid)*2 + 0], __ATOMIC_RELAXED, __HIP_MEMORY_SCOPE_AGENT);
        u64 p1 = __hip_atomic_load(&Pg[(k*32 + tid)*2 + 1], __ATOMIC_RELAXED, __HIP_MEMORY_SCOPE_AGENT);
        s1 += __uint_as_float((u32)p0); q1 += __uint_as_float((u32)(p0 >> 32));
        s2 += __uint_as_float((u32)p1); q2 += __uint_as_float((u32)(p1 >> 32));
      }
      float mu1 = s1*(1.f/768.f), rs1 = rsqrtf(q1*(1.f/768.f)-mu1*mu1+1e-5f);
      float mu2 = s2*(1.f/384.f), rs2 = rsqrtf(q2*(1.f/384.f)-mu2*mu2+1e-5f);
      stats_lds[tid] = make_float4(mu1, rs1, mu2, rs2);
    }
    __syncthreads();

    // ---- phase 5: gates + h update + WT-atomic h publish ----
    if (is_n){
      #pragma unroll
      for (int mt=0;mt<2;mt++)
        #pragma unroll
        for (int j=0;j<4;j++){
          int p = mt*4+j, row = lg*4+j, bg = mt*16+row;
          float4 st4 = stats_lds[bg];
          float rpre = S_lds[nt][0][mt][row][lc];
          float zpre = S_lds[nt][1][mt][row][lc];
          float gr = 1.f/(1.f + __expf(-(a_r[p] + (rpre - st4.x)*st4.y*G1r + B1r)));
          float gz = 1.f/(1.f + __expf(-(a_z[p] + (zpre - st4.x)*st4.y*G1z + B1z)));
          float nv = tanhf(a_n[p] + gr*((accn[mt][j] - st4.z)*st4.w*G2v + B2v));
          float hn = (1.f - gz)*nv + gz*hprev[p];
          hprev[p] = hn;
          outr[((long)((bbase+bg)*256+s_t))*768 + dir*384 + u] = hn;
          u16 hi = f2b(hn); u16 lo = f2b(hn - b2f(hi));
          __hip_atomic_store(&hg[bg*384 + u], (u32)hi | ((u32)lo << 16),
                             __ATOMIC_RELAXED, __HIP_MEMORY_SCOPE_AGENT);
        }
    }
    gsync(ctrg, (u32)(8*(2*step+2)));
  }
}

// ---------------- final LN over 768 (f32 in), f32 out ----------------
__global__ __launch_bounds__(128) void k_lnout(
    const float* __restrict__ hr, const float* __restrict__ g, const float* __restrict__ bb,
    float* __restrict__ out)
{
  long row = blockIdx.x;
  const float* r = hr + row*768;
  int t = threadIdx.x;
  __shared__ float red[2][2];
  float s=0, q=0;
  float4 va, vb;
  if (t < 96){
    va = *(const float4*)(r + t*8);
    vb = *(const float4*)(r + t*8 + 4);
    s = va.x+va.y+va.z+va.w + vb.x+vb.y+vb.z+vb.w;
    q = va.x*va.x+va.y*va.y+va.z*va.z+va.w*va.w
      + vb.x*vb.x+vb.y*vb.y+vb.z*vb.z+vb.w*vb.w;
  }
  int lane = t & 63, wid = t >> 6;
  #pragma unroll
  for (int o=32;o>0;o>>=1){ s += __shfl_down(s,o); q += __shfl_down(q,o); }
  if (lane == 0){ red[wid][0]=s; red[wid][1]=q; }
  __syncthreads();
  float S = red[0][0]+red[1][0], Q = red[0][1]+red[1][1];
  float mu = S*(1.f/768.f), rs = rsqrtf(Q*(1.f/768.f) - mu*mu + 1e-5f);
  if (t < 96){
    float* op = out + row*768 + t*8;
    float iv[8] = {va.x,va.y,va.z,va.w,vb.x,vb.y,vb.z,vb.w};
    #pragma unroll
    for (int j=0;j<8;j++) op[j] = (iv[j] - mu)*rs*g[t*8+j] + bb[t*8+j];
  }
}

extern "C" void kernel_launch(void* const* d_in, const int* in_sizes, int n_in,
                              void* d_out, int out_size, void* d_ws, size_t ws_size,
                              hipStream_t stream){
  const float* x     = (const float*)d_in[0];
  const float* cw3   = (const float*)d_in[1];
  const float* cb3   = (const float*)d_in[2];
  const float* cw5   = (const float*)d_in[3];
  const float* cb5   = (const float*)d_in[4];
  const float* cw7   = (const float*)d_in[5];
  const float* cb7   = (const float*)d_in[6];
  const float* wxrz  = (const float*)d_in[7];
  const float* bxrz  = (const float*)d_in[8];
  const float* whrz  = (const float*)d_in[9];
  const float* bhrz  = (const float*)d_in[10];
  const float* wxn   = (const float*)d_in[11];
  const float* bxn   = (const float*)d_in[12];
  const float* whn   = (const float*)d_in[13];
  const float* bhn   = (const float*)d_in[14];
  const float* lnx1g = (const float*)d_in[15];
  const float* lnx1b = (const float*)d_in[16];
  const float* lnh1g = (const float*)d_in[17];
  const float* lnh1b = (const float*)d_in[18];
  const float* lnx2g = (const float*)d_in[19];
  const float* lnx2b = (const float*)d_in[20];
  const float* lnh2g = (const float*)d_in[21];
  const float* lnh2b = (const float*)d_in[22];
  const float* lnog  = (const float*)d_in[23];
  const float* lnob  = (const float*)d_in[24];

  char* w = (char*)d_ws;
  auto alloc = [&](size_t bytes)->char*{ char* p = w; w += (bytes + 255) & ~(size_t)255; return p; };
  // persistent (live through k_gru2):
  float* sc   = (float*)alloc(32768L*1152*4);     // 151 MB scores -> a
  u16*  wrzf  = (u16*) alloc(8L*3*2*12*512*2);
  u16*  wnf   = (u16*) alloc(8L*3*2*12*512*2);
  u32*  hglob = (u32*) alloc(8L*32*384*4);        // 384 KB packed hi/lo
  u64*  P     = (u64*) alloc(8L*8*32*2*8);        // 32 KB
  u32*  ctr   = (u32*) alloc(8*4);
  // transient (dead after main GEMM) — outr aliases:
  char* regionA = w;
  u16*  xp   = (u16*) alloc(128L*262*768*2);
  u16*  weff = (u16*) alloc(1152L*5376*2);
  float* V   = (float*)alloc(7L*768*768*4);
  float* beff= (float*)alloc(1152*4);
  float* outr = (float*)regionA;

  k_zero<<<(8*32*384 + 255)/256, 256, 0, stream>>>(hglob, 8*32*384);
  k_zero<<<1, 8, 0, stream>>>(ctr, 8);

  k_pad_cast<<<12576, 256, 0, stream>>>(x, xp);
  k_build_v<<<16128, 256, 0, stream>>>(cw3, cw5, cw7, V);
  k_weff<<<dim3(12,18,7), 256, 0, stream>>>(wxrz, wxn, V, weff);
  k_beff<<<5, 256, 0, stream>>>(wxrz, wxn, bxrz, bxn, cb3, cb5, cb7, beff);
  k_pack_wrzf<<<1152, 256, 0, stream>>>(whrz, wrzf);
  k_pack_wnf<<<1152, 256, 0, stream>>>(whn, wnf);

  k_gemm<true><<<dim3(256,9), 256, 0, stream>>>(xp, 262L*768, 768, weff, 5376, beff, sc, 1152, 0);
  k_ln1<<<32768, 192, 0, stream>>>(sc, lnx1g, lnx1b, lnx2g, lnx2b);
  k_gru2<<<64, 512, 0, stream>>>(sc, wrzf, wnf, bhrz, bhn, lnh1g, lnh1b, lnh2g, lnh2b,
                                 outr, hglob, P, ctr);
  k_lnout<<<32768, 128, 0, stream>>>(outr, lnog, lnob, (float*)d_out);
}